// Round 15
// baseline (51.959 us; speedup 1.0000x reference)
//
#include <hip/hip_runtime.h>
#include <hip/hip_bf16.h>
#include <stdint.h>

typedef __attribute__((ext_vector_type(8))) short bf16x8;
typedef __attribute__((ext_vector_type(4))) float f32x4;
typedef __attribute__((ext_vector_type(16))) float f32x16;

#define MFMA32(a, b, c) __builtin_amdgcn_mfma_f32_32x32x16_bf16((a), (b), (c), 0, 0, 0)

union UF { unsigned int d[4]; bf16x8 v; };

__device__ __forceinline__ unsigned short f2bf_rn(float f) {
    union { __bf16 b; unsigned short u; } v;
    v.b = (__bf16)f;
    return v.u;
}

// pack 2 floats -> 2 bf16 in a uint (compiler fuses to v_cvt_pk_bf16_f32)
__device__ __forceinline__ unsigned int pk2(float lo, float hi) {
    union { unsigned short s[2]; unsigned int u; } r;
    r.s[0] = f2bf_rn(lo); r.s[1] = f2bf_rn(hi);
    return r.u;
}

__device__ __forceinline__ void gload_lds16(const void* g, void* l) {
    __builtin_amdgcn_global_load_lds(
        (const __attribute__((address_space(1))) void*)g,
        (__attribute__((address_space(3))) void*)l, 16, 0, 0);
}

// ---------------------------------------------------------------------------
// prep_h: transpose each 128x128 fp32 block of the 8 H tensors to bf16.
//   ht[j][blk][k][r] = h_j[blk][r][k]
// 256 WGs = jblk(64) x k-quarter(4).
// ---------------------------------------------------------------------------
__global__ __launch_bounds__(256) void prep_h(
    const float* __restrict__ h0, const float* __restrict__ h1,
    const float* __restrict__ h2, const float* __restrict__ h3,
    const float* __restrict__ h4, const float* __restrict__ h5,
    const float* __restrict__ h6, const float* __restrict__ h7,
    unsigned short* __restrict__ ht)
{
    const float* hmap[8] = {h0, h1, h2, h3, h4, h5, h6, h7};
    const int wg = blockIdx.x;            // 256 = jblk(64) x quarter(4)
    const int jblk = wg >> 2, qt = wg & 3;
    const float* src = hmap[jblk >> 3] + (jblk & 7) * 16384;
    unsigned short* dst = ht + jblk * 16384;
    __shared__ unsigned short tile[32 * 129];
    const int t = threadIdx.x;
    #pragma unroll
    for (int i = 0; i < 16; ++i) {
        int idx = t + 256 * i;            // 4096 = r(128) x kk(32)
        int r = idx >> 5, kk = idx & 31;
        tile[kk * 129 + r] = f2bf_rn(src[r * 128 + qt * 32 + kk]);
    }
    __syncthreads();
    #pragma unroll
    for (int i = 0; i < 16; ++i) {
        int idx = t + 256 * i;            // 4096 = k(32) x r(128)
        int k = idx >> 7, r = idx & 127;
        dst[(qt * 32 + k) * 128 + r] = tile[k * 129 + r];
    }
}

// ---------------------------------------------------------------------------
// bilin_main: 256 WGs = (b,p,q), q = bid&7 (XCD-locked). 256 threads =
// 4 waves, wave wn owns output cols wn*32..+32, full K=128. 32x32x16 MFMA.
// R15 = R14's paired phases with DUAL-u (fixes R14's shared-u serial chain):
//   4 phases of (c_re, c_im) sharing one X plane:
//   P0=(c0,c6) P1=(c1,c7) on Xre; P2=(c2,c4) P3=(c3,c5) on Xim.
//   Phase: [stage lre/lim(ph)] A(re)->u_re; A(im)->u_im; ufu_re=build(u_re);
//          ufu_im=build(u_im)   (u's die BEFORE the barrier; ufu_re's shfl
//          chain hides under A(im)'s MFMAs)
//          | MID (drains lre/lim) | [stage wre/wim(ph+1)]
//          Bgrid(lre,ufu_re)->yre ; Bgrid(lim,ufu_im)->yim   (two fully
//          independent ldr->MFMA chains: different Lt tiles, different y)
//          | END (drains wre/wim(ph+1)) |
// Cross-barrier live regs: xf 128 + y 128 + ufu 64 = 320 (R13-level; avoids
// the R12 allocator failure).  Barriers: 9 total.
// Xim path (R14-verified): prologue converts both planes from one fp32
// read; re->xplane, im->ximws (pre-swizzled).  Restage issued top of P1,
// drains MID(1); xf switched to im right after (readers start at P2).
// LDS = X 32K | wre 32K | wim 32K | lre 32K | lim 32K = 160 KB exact.
// LDS swizzle: 16B chunk ch of row at LDS[row][ch] = G[row][ch ^ (row&15)].
// ---------------------------------------------------------------------------
__global__ __launch_bounds__(256, 1) void bilin_main(
    const float* __restrict__ x, const int* __restrict__ perm,
    const unsigned short* __restrict__ ht,
    unsigned short* __restrict__ ximws,
    float* __restrict__ out)
{
    const int wg = blockIdx.x;
    const int q = wg & 7, p = (wg >> 3) & 7, b = wg >> 6;
    const int tid = threadIdx.x;
    const int lane = tid & 63, wn = tid >> 6;      // 4 waves
    const int l31 = lane & 31, hl = lane >> 5;

    __shared__ __align__(16) unsigned short smem[81920];   // 160 KB
    unsigned short* xplane = smem;                         // 32 KB
    unsigned short* wre = smem + 16384;
    unsigned short* wim = smem + 32768;
    unsigned short* lre = smem + 49152;
    unsigned short* lim = smem + 65536;

    // phase tables: re-target c (accumulates yre), im-target c (yim)
    constexpr int pre_c[4] = {0, 1, 2, 3};
    constexpr int pim_c[4] = {6, 7, 4, 5};
    constexpr int rperm[8] = {0, 1, 3, 2, 4, 5, 7, 6};

    // ---- staging helpers (gload_lds: wave-uniform LDS base + lane*16) ----
    const int wubase = tid & ~63;
    auto stage_h = [&](unsigned short* dst, int blk) {
        const unsigned short* src = ht + blk * 16384;
        #pragma unroll
        for (int r = 0; r < 8; ++r) {
            const int idx = r * 256 + tid;          // 16B chunk 0..2047
            const int row = idx >> 4, cin = idx & 15;
            gload_lds16(src + row * 128 + ((cin ^ (row & 15)) << 3),
                        dst + ((r * 256 + wubase) << 3));
        }
    };

    // swizzled LDS fragment read: row in [0,128), chunk in [0,16)
    auto ldr = [&](const unsigned short* base, int row, int ch) -> bf16x8 {
        return *(const bf16x8*)(base + row * 128 + ((ch ^ (row & 15)) << 3));
    };

    unsigned short* myxim = ximws + (size_t)wg * 16384;

    // fused prep_x: one fp32 read -> re plane to LDS, im plane (pre-swizzled
    // layout) to the global workspace for later zero-cost gload restage.
    auto stage_x_both = [&]() {
        #pragma unroll
        for (int i = 0; i < 8; ++i) {
            const int idx = i * 256 + tid;
            const int row = idx >> 4, cin = idx & 15;
            const int n1 = perm[2 * p + (row >> 6)];
            const int n2 = perm[2 * q + (cin >> 3)];
            const int r1 = row & 63, r2 = (cin & 7) * 8;
            const float* sp = x + ((size_t)((b * 16 + n1) * 64 + r1) * 1024
                                   + n2 * 64 + r2) * 2;
            float4 v0 = *(const float4*)(sp);
            float4 v1 = *(const float4*)(sp + 4);
            float4 v2 = *(const float4*)(sp + 8);
            float4 v3 = *(const float4*)(sp + 12);
            bf16x8 re, im;
            re[0] = (short)f2bf_rn(v0.x); re[1] = (short)f2bf_rn(v0.z);
            re[2] = (short)f2bf_rn(v1.x); re[3] = (short)f2bf_rn(v1.z);
            re[4] = (short)f2bf_rn(v2.x); re[5] = (short)f2bf_rn(v2.z);
            re[6] = (short)f2bf_rn(v3.x); re[7] = (short)f2bf_rn(v3.z);
            im[0] = (short)f2bf_rn(v0.y); im[1] = (short)f2bf_rn(v0.w);
            im[2] = (short)f2bf_rn(v1.y); im[3] = (short)f2bf_rn(v1.w);
            im[4] = (short)f2bf_rn(v2.y); im[5] = (short)f2bf_rn(v2.w);
            im[6] = (short)f2bf_rn(v3.y); im[7] = (short)f2bf_rn(v3.w);
            const int woff = row * 128 + ((cin ^ (row & 15)) << 3);
            *(bf16x8*)(xplane + woff) = re;
            *(bf16x8*)(myxim + woff) = im;
        }
    };

    // restage xim workspace -> xplane (linear gloads; layout pre-swizzled)
    auto restage_xim = [&]() {
        #pragma unroll
        for (int r = 0; r < 8; ++r) {
            const int idx = r * 256 + tid;
            gload_lds16(myxim + ((size_t)idx << 3),
                        xplane + ((r * 256 + wubase) << 3));
        }
    };

    // X fragments for the whole 128-row tile, in registers (128 VGPRs)
    bf16x8 xf[4][8];
    auto load_xf = [&]() {
        #pragma unroll
        for (int m2 = 0; m2 < 4; ++m2)
            #pragma unroll
            for (int ks = 0; ks < 8; ++ks)
                xf[m2][ks] = ldr(xplane, m2 * 32 + l31, 2 * ks + hl);
    };

    // stage A: u = X . W_c (full K=128), wfr batched (R13-verified)
    auto do_A = [&](const unsigned short* wb, f32x16 (&u)[4]) {
        bf16x8 wfr[8];
        #pragma unroll
        for (int ks = 0; ks < 8; ++ks)
            wfr[ks] = ldr(wb, wn * 32 + l31, 2 * ks + hl);
        #pragma unroll
        for (int m2 = 0; m2 < 4; ++m2)
            #pragma unroll
            for (int e = 0; e < 16; ++e) u[m2][e] = 0.f;
        #pragma unroll
        for (int ks = 0; ks < 8; ++ks)
            #pragma unroll
            for (int m2 = 0; m2 < 4; ++m2)
                u[m2] = MFMA32(xf[m2][ks], wfr[ks], u[m2]);
    };

    // build the 8 transposed B-frags from U (cvt-pack + 2-shfl, R13-verified)
    auto build_ufu = [&](const f32x16 (&u)[4], UF (&ufu)[8]) {
        #pragma unroll
        for (int t = 0; t < 8; ++t) {
            const int f = t >> 1, qa = (t & 1) * 2, qb = qa + 1;
            unsigned int lo0 = pk2(u[f][4 * qa + 0], u[f][4 * qa + 1]);
            unsigned int lo1 = pk2(u[f][4 * qa + 2], u[f][4 * qa + 3]);
            unsigned int hi0 = pk2(u[f][4 * qb + 0], u[f][4 * qb + 1]);
            unsigned int hi1 = pk2(u[f][4 * qb + 2], u[f][4 * qb + 3]);
            unsigned int send0 = hl ? lo0 : hi0;
            unsigned int send1 = hl ? lo1 : hi1;
            unsigned int sx0 = (unsigned int)__shfl_xor((int)send0, 32);
            unsigned int sx1 = (unsigned int)__shfl_xor((int)send1, 32);
            ufu[t].d[0] = hl ? sx0 : lo0;
            ufu[t].d[1] = hl ? sx1 : lo1;
            ufu[t].d[2] = hl ? hi0 : sx0;
            ufu[t].d[3] = hl ? hi1 : sx1;
        }
    };

    // stage-B MFMA grid: y += Lt . U  (lfr from LDS, B-frags in regs)
    auto do_Bgrid = [&](const UF (&ufu)[8], const unsigned short* lb,
                        f32x16 (&y)[4]) {
        #pragma unroll
        for (int t = 0; t < 8; ++t) {
            #pragma unroll
            for (int mt = 0; mt < 4; ++mt) {
                bf16x8 lfr = ldr(lb, mt * 32 + l31, 2 * t + hl);
                y[mt] = MFMA32(lfr, ufu[t].v, y[mt]);
            }
        }
    };

    // ---- prologue: W tiles of P0 + X (re->LDS, im->ws) ----
    stage_h(wre, rperm[pre_c[0]] * 8 + q);
    stage_h(wim, rperm[pim_c[0]] * 8 + q);
    stage_x_both();
    __syncthreads();       // drains W gloads; vmcnt covers myxim stores
    load_xf();             // xf = Xre; xplane now dead until restage

    f32x16 yre[4], yim[4];
    #pragma unroll
    for (int i = 0; i < 4; ++i)
        #pragma unroll
        for (int e = 0; e < 16; ++e) { yre[i][e] = 0.f; yim[i][e] = 0.f; }

    #pragma unroll
    for (int ph = 0; ph < 4; ++ph) {
        // stage this phase's Lt tiles (drain at MID; lre/lim(ph-1) were
        // last read before END(ph-1) -> overwrite-safe)
        stage_h(lre, pre_c[ph] * 8 + p);
        stage_h(lim, pim_c[ph] * 8 + p);
        if (ph == 1)
            restage_xim();   // xplane dead; drains at MID(1)

        // ---- A-block: two independent U's (ufu_re shfl chain hides
        // under A(im)'s MFMAs); u's die before the barrier
        f32x16 u[4];
        UF ufu_re[8], ufu_im[8];
        do_A(wre, u);
        build_ufu(u, ufu_re);
        do_A(wim, u);
        build_ufu(u, ufu_im);

        __syncthreads();   // MID: drains lre/lim(ph) (+restage at ph==1)

        if (ph < 3) {      // wre/wim last read in A-block -> overwrite-safe
            stage_h(wre, rperm[pre_c[ph + 1]] * 8 + q);
            stage_h(wim, rperm[pim_c[ph + 1]] * 8 + q);
        }
        if (ph == 1)
            load_xf();      // xf = Xim (xplane ready since MID(1); first
                            // reader is A-block of P2)

        // ---- B-block: two fully independent ldr->MFMA chains
        do_Bgrid(ufu_re, lre, yre);
        do_Bgrid(ufu_im, lim, yim);

        __syncthreads();   // END: drains wre/wim(ph+1); orders lre/lim reuse
    }

    // ---- epilogue: direct interleaved (re,im) stores, no reduction ----
    float2* o2 = (float2*)out;
    #pragma unroll
    for (int mt = 0; mt < 4; ++mt)
        #pragma unroll
        for (int j = 0; j < 16; ++j) {
            const int row = mt * 32 + (j & 3) + 8 * (j >> 2) + 4 * hl;
            float2 v;
            v.x = yre[mt][j];
            v.y = yim[mt][j];
            o2[(size_t)(b * 1024 + p * 128 + row) * 1024
               + q * 128 + wn * 32 + l31] = v;
        }
}

extern "C" void kernel_launch(void* const* d_in, const int* in_sizes, int n_in,
                              void* d_out, int out_size, void* d_ws, size_t ws_size,
                              hipStream_t stream) {
    const float* x  = (const float*)d_in[0];
    const int* perm = (const int*)d_in[1];
    unsigned short* ws = (unsigned short*)d_ws;
    // workspace (ushort units): ht 1M (2 MB) | ximws 4M (8 MB)
    unsigned short* htp   = ws;
    unsigned short* ximws = ws + 1024u * 1024u;

    hipLaunchKernelGGL(prep_h, dim3(256), dim3(256), 0, stream,
        (const float*)d_in[2], (const float*)d_in[3], (const float*)d_in[4],
        (const float*)d_in[5], (const float*)d_in[6], (const float*)d_in[7],
        (const float*)d_in[8], (const float*)d_in[9], htp);
    hipLaunchKernelGGL(bilin_main, dim3(256), dim3(256), 0, stream,
        x, perm, htp, ximws, (float*)d_out);
}

// Round 16
// 40.020 us; speedup vs baseline: 1.2983x; 1.2983x over previous
//
#include <hip/hip_runtime.h>
#include <hip/hip_bf16.h>
#include <stdint.h>

typedef __attribute__((ext_vector_type(8))) short bf16x8;
typedef __attribute__((ext_vector_type(4))) float f32x4;
typedef __attribute__((ext_vector_type(16))) float f32x16;

#define MFMA32(a, b, c) __builtin_amdgcn_mfma_f32_32x32x16_bf16((a), (b), (c), 0, 0, 0)

__device__ __forceinline__ unsigned short f2bf_rn(float f) {
    union { __bf16 b; unsigned short u; } v;
    v.b = (__bf16)f;
    return v.u;
}

// pack 2 floats -> 2 bf16 in a uint (compiler fuses to v_cvt_pk_bf16_f32)
__device__ __forceinline__ unsigned int pk2(float lo, float hi) {
    union { unsigned short s[2]; unsigned int u; } r;
    r.s[0] = f2bf_rn(lo); r.s[1] = f2bf_rn(hi);
    return r.u;
}

__device__ __forceinline__ void gload_lds16(const void* g, void* l) {
    __builtin_amdgcn_global_load_lds(
        (const __attribute__((address_space(1))) void*)g,
        (__attribute__((address_space(3))) void*)l, 16, 0, 0);
}

// ---------------------------------------------------------------------------
// prep_h: transpose each 128x128 fp32 block of the 8 H tensors to bf16.
//   ht[j][blk][k][r] = h_j[blk][r][k]
// 256 WGs = jblk(64) x k-quarter(4).
// ---------------------------------------------------------------------------
__global__ __launch_bounds__(256) void prep_h(
    const float* __restrict__ h0, const float* __restrict__ h1,
    const float* __restrict__ h2, const float* __restrict__ h3,
    const float* __restrict__ h4, const float* __restrict__ h5,
    const float* __restrict__ h6, const float* __restrict__ h7,
    unsigned short* __restrict__ ht)
{
    const float* hmap[8] = {h0, h1, h2, h3, h4, h5, h6, h7};
    const int wg = blockIdx.x;            // 256 = jblk(64) x quarter(4)
    const int jblk = wg >> 2, qt = wg & 3;
    const float* src = hmap[jblk >> 3] + (jblk & 7) * 16384;
    unsigned short* dst = ht + jblk * 16384;
    __shared__ unsigned short tile[32 * 129];
    const int t = threadIdx.x;
    #pragma unroll
    for (int i = 0; i < 16; ++i) {
        int idx = t + 256 * i;            // 4096 = r(128) x kk(32)
        int r = idx >> 5, kk = idx & 31;
        tile[kk * 129 + r] = f2bf_rn(src[r * 128 + qt * 32 + kk]);
    }
    __syncthreads();
    #pragma unroll
    for (int i = 0; i < 16; ++i) {
        int idx = t + 256 * i;            // 4096 = k(32) x r(128)
        int k = idx >> 7, r = idx & 127;
        dst[(qt * 32 + k) * 128 + r] = tile[k * 129 + r];
    }
}

// ---------------------------------------------------------------------------
// bilin_main: 256 WGs = (b,p,q), q = bid&7 (XCD-locked). 256 threads =
// 4 waves, wave wn owns output cols wn*32..+32, full K=128. 32x32x16 MFMA.
// R16 = R13's exact compute code (allocator-proven batched stages) with the
// ONE-barrier-per-c schedule, enabled by freeing the Xim LDS plane via the
// R14/R15-verified ximws path:
//   LDS = xplane 32K | W dbuf 2x32K | Lt dbuf 2x32K = 160 KB exact.
//   cc loop: [issue W(cc+1), Lt(cc+1) into opposite-parity buffers]
//            stage A from W[cc&1]  (batched wfr + 32 MFMA -> u)
//            (cc==3: reload xf <- xplane(im), hidden under stage B)
//            build ufu[8]; stage B from Lt[cc&1] (lfr ping-pong) -> y
//            END barrier (drains the top-of-cc stages; full c-term cover)
//   Barriers: 17 (R13) -> 10.
// Xim path: prologue converts both planes from one fp32 read; re->xplane,
// im->ximws (pre-swizzled).  Restage issued top of cc=1 (xplane dead since
// prologue load_xf), drains END(1); xf switched mid-cc=3 (A(3) done with
// re; B(3) MFMAs hide the 32 loads); first im reader is A(4).
// Regs: xf 128 + y 128 + transient u/ufu/wfr/lfr ~= R13 level (no spill).
// LDS swizzle: 16B chunk ch of row at LDS[row][ch] = G[row][ch ^ (row&15)].
// ---------------------------------------------------------------------------
__global__ __launch_bounds__(256, 1) void bilin_main(
    const float* __restrict__ x, const int* __restrict__ perm,
    const unsigned short* __restrict__ ht,
    unsigned short* __restrict__ ximws,
    float* __restrict__ out)
{
    const int wg = blockIdx.x;
    const int q = wg & 7, p = (wg >> 3) & 7, b = wg >> 6;
    const int tid = threadIdx.x;
    const int lane = tid & 63, wn = tid >> 6;      // 4 waves
    const int l31 = lane & 31, hl = lane >> 5;

    __shared__ __align__(16) unsigned short smem[81920];   // 160 KB
    unsigned short* xplane = smem;                         // 32 KB
    // W[par]  = smem + 16384 + par*16384   (64 KB)
    // Lt[par] = smem + 49152 + par*16384   (64 KB)

    constexpr int cseq[8]  = {0, 1, 6, 7, 2, 3, 4, 5};
    constexpr int rperm[8] = {0, 1, 3, 2, 4, 5, 7, 6};

    // ---- staging helpers (gload_lds: wave-uniform LDS base + lane*16) ----
    const int wubase = tid & ~63;
    auto stage_h = [&](unsigned short* dst, int blk) {
        const unsigned short* src = ht + blk * 16384;
        #pragma unroll
        for (int r = 0; r < 8; ++r) {
            const int idx = r * 256 + tid;          // 16B chunk 0..2047
            const int row = idx >> 4, cin = idx & 15;
            gload_lds16(src + row * 128 + ((cin ^ (row & 15)) << 3),
                        dst + ((r * 256 + wubase) << 3));
        }
    };

    // swizzled LDS fragment read: row in [0,128), chunk in [0,16)
    auto ldr = [&](const unsigned short* base, int row, int ch) -> bf16x8 {
        return *(const bf16x8*)(base + row * 128 + ((ch ^ (row & 15)) << 3));
    };

    unsigned short* myxim = ximws + (size_t)wg * 16384;

    // fused prep_x: one fp32 read -> re plane to LDS, im plane (pre-swizzled
    // layout) to the global workspace for later zero-cost gload restage.
    auto stage_x_both = [&]() {
        #pragma unroll
        for (int i = 0; i < 8; ++i) {
            const int idx = i * 256 + tid;
            const int row = idx >> 4, cin = idx & 15;
            const int n1 = perm[2 * p + (row >> 6)];
            const int n2 = perm[2 * q + (cin >> 3)];
            const int r1 = row & 63, r2 = (cin & 7) * 8;
            const float* sp = x + ((size_t)((b * 16 + n1) * 64 + r1) * 1024
                                   + n2 * 64 + r2) * 2;
            float4 v0 = *(const float4*)(sp);
            float4 v1 = *(const float4*)(sp + 4);
            float4 v2 = *(const float4*)(sp + 8);
            float4 v3 = *(const float4*)(sp + 12);
            bf16x8 re, im;
            re[0] = (short)f2bf_rn(v0.x); re[1] = (short)f2bf_rn(v0.z);
            re[2] = (short)f2bf_rn(v1.x); re[3] = (short)f2bf_rn(v1.z);
            re[4] = (short)f2bf_rn(v2.x); re[5] = (short)f2bf_rn(v2.z);
            re[6] = (short)f2bf_rn(v3.x); re[7] = (short)f2bf_rn(v3.z);
            im[0] = (short)f2bf_rn(v0.y); im[1] = (short)f2bf_rn(v0.w);
            im[2] = (short)f2bf_rn(v1.y); im[3] = (short)f2bf_rn(v1.w);
            im[4] = (short)f2bf_rn(v2.y); im[5] = (short)f2bf_rn(v2.w);
            im[6] = (short)f2bf_rn(v3.y); im[7] = (short)f2bf_rn(v3.w);
            const int woff = row * 128 + ((cin ^ (row & 15)) << 3);
            *(bf16x8*)(xplane + woff) = re;
            *(bf16x8*)(myxim + woff) = im;
        }
    };

    // restage xim workspace -> xplane (linear gloads; layout pre-swizzled)
    auto restage_xim = [&]() {
        #pragma unroll
        for (int r = 0; r < 8; ++r) {
            const int idx = r * 256 + tid;
            gload_lds16(myxim + ((size_t)idx << 3),
                        xplane + ((r * 256 + wubase) << 3));
        }
    };

    // X fragments for the whole 128-row tile, in registers (128 VGPRs)
    bf16x8 xf[4][8];
    auto load_xf = [&]() {
        #pragma unroll
        for (int m2 = 0; m2 < 4; ++m2)
            #pragma unroll
            for (int ks = 0; ks < 8; ++ks)
                xf[m2][ks] = ldr(xplane, m2 * 32 + l31, 2 * ks + hl);
    };

    // ---- prologue ----
    stage_h(smem + 16384, rperm[cseq[0]] * 8 + q);   // W(0) -> W[0]
    stage_h(smem + 49152, cseq[0] * 8 + p);          // Lt(0) -> Lt[0]
    stage_x_both();
    __syncthreads();          // drains gloads + vmcnt covers myxim stores
    load_xf();                // xf = Xre; xplane dead until restage

    f32x16 yre[4], yim[4];
    #pragma unroll
    for (int i = 0; i < 4; ++i) {
        #pragma unroll
        for (int e = 0; e < 16; ++e) { yre[i][e] = 0.f; yim[i][e] = 0.f; }
    }

    #pragma unroll
    for (int cc = 0; cc < 8; ++cc) {
        const unsigned short* wb = smem + 16384 + (cc & 1) * 16384;
        const unsigned short* lb = smem + 49152 + (cc & 1) * 16384;

        // issue next c's stages into opposite-parity buffers (last read in
        // cc-1, barrier END(cc-1) passed -> overwrite-safe); drain END(cc)
        if (cc < 7) {
            stage_h(smem + 16384 + ((cc + 1) & 1) * 16384,
                    rperm[cseq[cc + 1]] * 8 + q);
            stage_h(smem + 49152 + ((cc + 1) & 1) * 16384,
                    cseq[cc + 1] * 8 + p);
        }
        if (cc == 1)
            restage_xim();    // xplane dead since prologue; drains END(1)

        // ---- stage A: preload all 8 wfr (independent), then 32 MFMAs
        bf16x8 wfr[8];
        #pragma unroll
        for (int ks = 0; ks < 8; ++ks)
            wfr[ks] = ldr(wb, wn * 32 + l31, 2 * ks + hl);
        f32x16 u[4];
        #pragma unroll
        for (int m2 = 0; m2 < 4; ++m2)
            #pragma unroll
            for (int e = 0; e < 16; ++e) u[m2][e] = 0.f;
        #pragma unroll
        for (int ks = 0; ks < 8; ++ks)
            #pragma unroll
            for (int m2 = 0; m2 < 4; ++m2)
                u[m2] = MFMA32(xf[m2][ks], wfr[ks], u[m2]);

        // g switch: A(3) was xf(re)'s last use; reload im fragments now so
        // the 32 LDS loads hide under stage B(3)'s MFMAs (xplane restaged
        // during cc=1, drained at END(1)).  First im reader is A(4).
        if (cc == 3) load_xf();

        // ---- stage B: build ALL 8 B-frags first (shfl latencies overlap
        // once), then the 8x4 MFMA grid with lfr ping-pong lookahead.
        union UF { unsigned int d[4]; bf16x8 v; };
        UF ufu[8];
        #pragma unroll
        for (int t = 0; t < 8; ++t) {
            const int f = t >> 1, qa = (t & 1) * 2, qb = qa + 1;
            unsigned int lo0 = pk2(u[f][4 * qa + 0], u[f][4 * qa + 1]);
            unsigned int lo1 = pk2(u[f][4 * qa + 2], u[f][4 * qa + 3]);
            unsigned int hi0 = pk2(u[f][4 * qb + 0], u[f][4 * qb + 1]);
            unsigned int hi1 = pk2(u[f][4 * qb + 2], u[f][4 * qb + 3]);
            unsigned int send0 = hl ? lo0 : hi0;
            unsigned int send1 = hl ? lo1 : hi1;
            unsigned int sx0 = (unsigned int)__shfl_xor((int)send0, 32);
            unsigned int sx1 = (unsigned int)__shfl_xor((int)send1, 32);
            ufu[t].d[0] = hl ? sx0 : lo0;
            ufu[t].d[1] = hl ? sx1 : lo1;
            ufu[t].d[2] = hl ? hi0 : sx0;
            ufu[t].d[3] = hl ? hi1 : sx1;
        }
        bf16x8 lcur[4], lnxt[4];
        #pragma unroll
        for (int mt = 0; mt < 4; ++mt)
            lcur[mt] = ldr(lb, mt * 32 + l31, hl);            // t=0
        #pragma unroll
        for (int t = 0; t < 8; ++t) {
            if (t < 7) {
                #pragma unroll
                for (int mt = 0; mt < 4; ++mt)
                    lnxt[mt] = ldr(lb, mt * 32 + l31, 2 * (t + 1) + hl);
            }
            const bool isRe = (cc & 3) < 2;
            #pragma unroll
            for (int mt = 0; mt < 4; ++mt) {
                if (isRe) yre[mt] = MFMA32(lcur[mt], ufu[t].v, yre[mt]);
                else      yim[mt] = MFMA32(lcur[mt], ufu[t].v, yim[mt]);
            }
            #pragma unroll
            for (int mt = 0; mt < 4; ++mt) lcur[mt] = lnxt[mt];
        }

        __syncthreads();   // END: orders dbuf parity reuse; drains the
                           // stages issued at the top of this cc
    }

    // ---- epilogue: direct interleaved (re,im) stores, no reduction ----
    float2* o2 = (float2*)out;
    #pragma unroll
    for (int mt = 0; mt < 4; ++mt)
        #pragma unroll
        for (int j = 0; j < 16; ++j) {
            const int row = mt * 32 + (j & 3) + 8 * (j >> 2) + 4 * hl;
            float2 v;
            v.x = yre[mt][j];
            v.y = yim[mt][j];
            o2[(size_t)(b * 1024 + p * 128 + row) * 1024
               + q * 128 + wn * 32 + l31] = v;
        }
}

extern "C" void kernel_launch(void* const* d_in, const int* in_sizes, int n_in,
                              void* d_out, int out_size, void* d_ws, size_t ws_size,
                              hipStream_t stream) {
    const float* x  = (const float*)d_in[0];
    const int* perm = (const int*)d_in[1];
    unsigned short* ws = (unsigned short*)d_ws;
    // workspace (ushort units): ht 1M (2 MB) | ximws 4M (8 MB)
    unsigned short* htp   = ws;
    unsigned short* ximws = ws + 1024u * 1024u;

    hipLaunchKernelGGL(prep_h, dim3(256), dim3(256), 0, stream,
        (const float*)d_in[2], (const float*)d_in[3], (const float*)d_in[4],
        (const float*)d_in[5], (const float*)d_in[6], (const float*)d_in[7],
        (const float*)d_in[8], (const float*)d_in[9], htp);
    hipLaunchKernelGGL(bilin_main, dim3(256), dim3(256), 0, stream,
        x, perm, htp, ximws, (float*)d_out);
}

// Round 17
// 38.160 us; speedup vs baseline: 1.3616x; 1.0488x over previous
//
#include <hip/hip_runtime.h>
#include <hip/hip_bf16.h>
#include <stdint.h>

typedef __attribute__((ext_vector_type(8))) short bf16x8;
typedef __attribute__((ext_vector_type(4))) float f32x4;
typedef __attribute__((ext_vector_type(16))) float f32x16;

#define MFMA32(a, b, c) __builtin_amdgcn_mfma_f32_32x32x16_bf16((a), (b), (c), 0, 0, 0)

__device__ __forceinline__ unsigned short f2bf_rn(float f) {
    union { __bf16 b; unsigned short u; } v;
    v.b = (__bf16)f;
    return v.u;
}

// pack 2 floats -> 2 bf16 in a uint (compiler fuses to v_cvt_pk_bf16_f32)
__device__ __forceinline__ unsigned int pk2(float lo, float hi) {
    union { unsigned short s[2]; unsigned int u; } r;
    r.s[0] = f2bf_rn(lo); r.s[1] = f2bf_rn(hi);
    return r.u;
}

__device__ __forceinline__ void gload_lds16(const void* g, void* l) {
    __builtin_amdgcn_global_load_lds(
        (const __attribute__((address_space(1))) void*)g,
        (__attribute__((address_space(3))) void*)l, 16, 0, 0);
}

// ---------------------------------------------------------------------------
// prep_h: transpose each 128x128 fp32 block of the 8 H tensors to bf16.
//   ht[j][blk][k][r] = h_j[blk][r][k]
// 256 WGs = jblk(64) x k-quarter(4).  R17: float4 reads / ushort4 writes.
// ---------------------------------------------------------------------------
__global__ __launch_bounds__(256) void prep_h(
    const float* __restrict__ h0, const float* __restrict__ h1,
    const float* __restrict__ h2, const float* __restrict__ h3,
    const float* __restrict__ h4, const float* __restrict__ h5,
    const float* __restrict__ h6, const float* __restrict__ h7,
    unsigned short* __restrict__ ht)
{
    const float* hmap[8] = {h0, h1, h2, h3, h4, h5, h6, h7};
    const int wg = blockIdx.x;            // 256 = jblk(64) x quarter(4)
    const int jblk = wg >> 2, qt = wg & 3;
    const float* src = hmap[jblk >> 3] + (jblk & 7) * 16384;
    unsigned short* dst = ht + jblk * 16384;
    __shared__ unsigned short tile[32 * 129];
    const int t = threadIdx.x;
    #pragma unroll
    for (int i = 0; i < 4; ++i) {
        int idx = t + 256 * i;            // 1024 = r(128) x kquad(8)
        int r = idx >> 3, kq = idx & 7;
        float4 v = *(const float4*)(src + r * 128 + qt * 32 + kq * 4);
        tile[(kq * 4 + 0) * 129 + r] = f2bf_rn(v.x);
        tile[(kq * 4 + 1) * 129 + r] = f2bf_rn(v.y);
        tile[(kq * 4 + 2) * 129 + r] = f2bf_rn(v.z);
        tile[(kq * 4 + 3) * 129 + r] = f2bf_rn(v.w);
    }
    __syncthreads();
    #pragma unroll
    for (int i = 0; i < 4; ++i) {
        int idx = t + 256 * i;            // 1024 = k(32) x rquad(32)
        int k = idx >> 5, rq = idx & 31;
        ushort4 o;
        o.x = tile[k * 129 + rq * 4 + 0];
        o.y = tile[k * 129 + rq * 4 + 1];
        o.z = tile[k * 129 + rq * 4 + 2];
        o.w = tile[k * 129 + rq * 4 + 3];
        *(ushort4*)(dst + (qt * 32 + k) * 128 + rq * 4) = o;
    }
}

// ---------------------------------------------------------------------------
// bilin_main: 256 WGs = (b,p,q), q = bid&7 (XCD-locked). 256 threads =
// 4 waves, wave wn owns output cols wn*32..+32, full K=128. 32x32x16 MFMA.
// R13 structure VERBATIM (best verified, 38.2 us):  both X planes resident
// in LDS, xf in REGISTERS per g; W double-buffered, Lt single-buffered,
// MID/END barriers; batched wfr; batched ufu build; lfr pipelined.
// R17 delta: the t=0/t=1 lfr batches load BEFORE the ufu build, hiding
// their LDS latency under the ~50-instr cvt/shfl chain; the MFMA grid runs
// a 2-deep lfr pipeline (same transient register count).
// LDS = Xre 32K | Xim 32K | W dbuf 64K | Lt 32K = 160 KB exact.
// LDS swizzle: 16B chunk ch of row at LDS[row][ch] = G[row][ch ^ (row&15)].
// ---------------------------------------------------------------------------
__global__ __launch_bounds__(256, 1) void bilin_main(
    const float* __restrict__ x, const int* __restrict__ perm,
    const unsigned short* __restrict__ ht, float* __restrict__ out)
{
    const int wg = blockIdx.x;
    const int q = wg & 7, p = (wg >> 3) & 7, b = wg >> 6;
    const int tid = threadIdx.x;
    const int lane = tid & 63, wn = tid >> 6;      // 4 waves
    const int l31 = lane & 31, hl = lane >> 5;

    __shared__ __align__(16) unsigned short smem[81920];   // 160 KB
    unsigned short* xre_lds = smem;                        // 32 KB
    unsigned short* xim_lds = smem + 16384;                // 32 KB
    // W[par] = smem + 32768 + par*16384 (64 KB)
    unsigned short* llds = smem + 65536;                   // 32 KB

    constexpr int cseq[8]  = {0, 1, 6, 7, 2, 3, 4, 5};
    constexpr int rperm[8] = {0, 1, 3, 2, 4, 5, 7, 6};

    // ---- staging helpers (gload_lds: wave-uniform LDS base + lane*16) ----
    const int wubase = tid & ~63;
    auto stage_h = [&](unsigned short* dst, int blk) {
        const unsigned short* src = ht + blk * 16384;
        #pragma unroll
        for (int r = 0; r < 8; ++r) {
            const int idx = r * 256 + tid;          // 16B chunk 0..2047
            const int row = idx >> 4, cin = idx & 15;
            gload_lds16(src + row * 128 + ((cin ^ (row & 15)) << 3),
                        dst + ((r * 256 + wubase) << 3));
        }
    };

    // swizzled LDS fragment read: row in [0,128), chunk in [0,16)
    auto ldr = [&](const unsigned short* base, int row, int ch) -> bf16x8 {
        return *(const bf16x8*)(base + row * 128 + ((ch ^ (row & 15)) << 3));
    };

    // fused prep_x: fp32 read ONCE -> convert -> both swizzled LDS planes
    auto stage_x_both = [&]() {
        #pragma unroll
        for (int i = 0; i < 8; ++i) {
            const int idx = i * 256 + tid;
            const int row = idx >> 4, cin = idx & 15;
            const int n1 = perm[2 * p + (row >> 6)];
            const int n2 = perm[2 * q + (cin >> 3)];
            const int r1 = row & 63, r2 = (cin & 7) * 8;
            const float* sp = x + ((size_t)((b * 16 + n1) * 64 + r1) * 1024
                                   + n2 * 64 + r2) * 2;
            float4 v0 = *(const float4*)(sp);
            float4 v1 = *(const float4*)(sp + 4);
            float4 v2 = *(const float4*)(sp + 8);
            float4 v3 = *(const float4*)(sp + 12);
            bf16x8 re, im;
            re[0] = (short)f2bf_rn(v0.x); re[1] = (short)f2bf_rn(v0.z);
            re[2] = (short)f2bf_rn(v1.x); re[3] = (short)f2bf_rn(v1.z);
            re[4] = (short)f2bf_rn(v2.x); re[5] = (short)f2bf_rn(v2.z);
            re[6] = (short)f2bf_rn(v3.x); re[7] = (short)f2bf_rn(v3.z);
            im[0] = (short)f2bf_rn(v0.y); im[1] = (short)f2bf_rn(v0.w);
            im[2] = (short)f2bf_rn(v1.y); im[3] = (short)f2bf_rn(v1.w);
            im[4] = (short)f2bf_rn(v2.y); im[5] = (short)f2bf_rn(v2.w);
            im[6] = (short)f2bf_rn(v3.y); im[7] = (short)f2bf_rn(v3.w);
            const int woff = row * 128 + ((cin ^ (row & 15)) << 3);
            *(bf16x8*)(xre_lds + woff) = re;
            *(bf16x8*)(xim_lds + woff) = im;
        }
    };

    // X fragments for the whole 128-row tile, in registers (128 VGPRs)
    bf16x8 xf[4][8];
    auto load_xf = [&](const unsigned short* plane) {
        #pragma unroll
        for (int m2 = 0; m2 < 4; ++m2)
            #pragma unroll
            for (int ks = 0; ks < 8; ++ks)
                xf[m2][ks] = ldr(plane, m2 * 32 + l31, 2 * ks + hl);
    };

    // ---- prologue ----
    stage_h(smem + 32768, rperm[0] * 8 + q);   // W(0)
    stage_h(llds, 0 * 8 + p);                  // Lt(0)
    stage_x_both();
    __syncthreads();          // drains gloads, orders X plane writes
    load_xf(xre_lds);

    f32x16 yre[4], yim[4];
    #pragma unroll
    for (int i = 0; i < 4; ++i) {
        #pragma unroll
        for (int e = 0; e < 16; ++e) { yre[i][e] = 0.f; yim[i][e] = 0.f; }
    }

    #pragma unroll
    for (int cc = 0; cc < 8; ++cc) {
        const unsigned short* wb = smem + 32768 + (cc & 1) * 16384;

        // issue next W (opposite parity, last read in stage A(cc-1)): drains
        // at this c's END barrier
        if (cc < 7)
            stage_h(smem + 32768 + ((cc + 1) & 1) * 16384,
                    rperm[cseq[cc + 1]] * 8 + q);

        // g switch: planes are static after prologue — plain reload
        if (cc == 4) load_xf(xim_lds);

        // ---- stage A: preload all 8 wfr (independent), then 32 MFMAs
        bf16x8 wfr[8];
        #pragma unroll
        for (int ks = 0; ks < 8; ++ks)
            wfr[ks] = ldr(wb, wn * 32 + l31, 2 * ks + hl);
        f32x16 u[4];
        #pragma unroll
        for (int m2 = 0; m2 < 4; ++m2)
            #pragma unroll
            for (int e = 0; e < 16; ++e) u[m2][e] = 0.f;
        #pragma unroll
        for (int ks = 0; ks < 8; ++ks)
            #pragma unroll
            for (int m2 = 0; m2 < 4; ++m2)
                u[m2] = MFMA32(xf[m2][ks], wfr[ks], u[m2]);

        __syncthreads();   // MID: drains Lt(c) (issued at END of cc-1)

        // ---- stage B (R17): issue t=0/t=1 lfr batches FIRST, build all
        // 8 B-frags while they fly, then the MFMA grid (2-deep pipeline).
        bf16x8 lcur[4], lnxt[4];
        #pragma unroll
        for (int mt = 0; mt < 4; ++mt)
            lcur[mt] = ldr(llds, mt * 32 + l31, hl);          // t=0
        #pragma unroll
        for (int mt = 0; mt < 4; ++mt)
            lnxt[mt] = ldr(llds, mt * 32 + l31, 2 + hl);      // t=1

        union UF { unsigned int d[4]; bf16x8 v; };
        UF ufu[8];
        #pragma unroll
        for (int t = 0; t < 8; ++t) {
            const int f = t >> 1, qa = (t & 1) * 2, qb = qa + 1;
            unsigned int lo0 = pk2(u[f][4 * qa + 0], u[f][4 * qa + 1]);
            unsigned int lo1 = pk2(u[f][4 * qa + 2], u[f][4 * qa + 3]);
            unsigned int hi0 = pk2(u[f][4 * qb + 0], u[f][4 * qb + 1]);
            unsigned int hi1 = pk2(u[f][4 * qb + 2], u[f][4 * qb + 3]);
            unsigned int send0 = hl ? lo0 : hi0;
            unsigned int send1 = hl ? lo1 : hi1;
            unsigned int sx0 = (unsigned int)__shfl_xor((int)send0, 32);
            unsigned int sx1 = (unsigned int)__shfl_xor((int)send1, 32);
            ufu[t].d[0] = hl ? sx0 : lo0;
            ufu[t].d[1] = hl ? sx1 : lo1;
            ufu[t].d[2] = hl ? hi0 : sx0;
            ufu[t].d[3] = hl ? hi1 : sx1;
        }
        const bool isRe = (cc & 3) < 2;
        #pragma unroll
        for (int t = 0; t < 8; ++t) {
            #pragma unroll
            for (int mt = 0; mt < 4; ++mt) {
                if (isRe) yre[mt] = MFMA32(lcur[mt], ufu[t].v, yre[mt]);
                else      yim[mt] = MFMA32(lcur[mt], ufu[t].v, yim[mt]);
            }
            #pragma unroll
            for (int mt = 0; mt < 4; ++mt) lcur[mt] = lnxt[mt];
            if (t < 6) {
                #pragma unroll
                for (int mt = 0; mt < 4; ++mt)
                    lnxt[mt] = ldr(llds, mt * 32 + l31, 2 * (t + 2) + hl);
            }
        }

        __syncthreads();   // END: all waves done with llds; drains W(c+1)
        if (cc < 7)
            stage_h(llds, cseq[cc + 1] * 8 + p);   // drains at MID(cc+1)
    }

    // ---- epilogue: direct interleaved (re,im) stores, no reduction ----
    float2* o2 = (float2*)out;
    #pragma unroll
    for (int mt = 0; mt < 4; ++mt)
        #pragma unroll
        for (int j = 0; j < 16; ++j) {
            const int row = mt * 32 + (j & 3) + 8 * (j >> 2) + 4 * hl;
            float2 v;
            v.x = yre[mt][j];
            v.y = yim[mt][j];
            o2[(size_t)(b * 1024 + p * 128 + row) * 1024
               + q * 128 + wn * 32 + l31] = v;
        }
}

extern "C" void kernel_launch(void* const* d_in, const int* in_sizes, int n_in,
                              void* d_out, int out_size, void* d_ws, size_t ws_size,
                              hipStream_t stream) {
    const float* x  = (const float*)d_in[0];
    const int* perm = (const int*)d_in[1];
    unsigned short* htp = (unsigned short*)d_ws;   // 2 MB

    hipLaunchKernelGGL(prep_h, dim3(256), dim3(256), 0, stream,
        (const float*)d_in[2], (const float*)d_in[3], (const float*)d_in[4],
        (const float*)d_in[5], (const float*)d_in[6], (const float*)d_in[7],
        (const float*)d_in[8], (const float*)d_in[9], htp);
    hipLaunchKernelGGL(bilin_main, dim3(256), dim3(256), 0, stream,
        x, perm, htp, (float*)d_out);
}